// Round 15
// baseline (792.904 us; speedup 1.0000x reference)
//
#include <hip/hip_runtime.h>
#include <hip/hip_bf16.h>
#include <hip/hip_fp8.h>

#define N_NODES 100000
#define N_EDGES 1600000
#define N_GRAPHS 2000
#define D_IN 600
#define D_H 300
#define D_OUT 2

#define NPAD 320        // padded hidden width (multiple of 64)
#define K1PAD 640       // padded K for layer-1 GEMM
#define K2PAD 320       // padded K for layer-2 GEMM
#define MPAD 100096     // 3128 * 32

typedef __bf16 bf16;
typedef __bf16 bf16x8 __attribute__((ext_vector_type(8)));
typedef float f32x4 __attribute__((ext_vector_type(4)));
typedef float f32x2 __attribute__((ext_vector_type(2)));

__device__ __forceinline__ unsigned char ff8(float f) {
    __hip_fp8_e4m3 t(f); return (unsigned char)t.__x;
}

// ---------------- degree counting ----------------
__global__ __launch_bounds__(256) void count_deg(const int* __restrict__ src,
                                                 const int* __restrict__ dst,
                                                 int* __restrict__ deg_out,
                                                 int* __restrict__ deg_in) {
    int e = blockIdx.x * blockDim.x + threadIdx.x;
    if (e < N_EDGES) {
        atomicAdd(&deg_out[src[e]], 1);
        atomicAdd(&deg_in[dst[e]], 1);
    }
}

// ---------------- per-block sums of deg_in ----------------
__global__ __launch_bounds__(256) void block_sum(const int* __restrict__ deg_in,
                                                 int* __restrict__ bsum) {
    __shared__ int s[256];
    int i = blockIdx.x * 256 + threadIdx.x;
    s[threadIdx.x] = (i < N_NODES) ? deg_in[i] : 0;
    __syncthreads();
    for (int off = 128; off; off >>= 1) {
        if (threadIdx.x < off) s[threadIdx.x] += s[threadIdx.x + off];
        __syncthreads();
    }
    if (threadIdx.x == 0) bsum[blockIdx.x] = s[0];
}

// ---------------- one-block LDS scan over block sums (replaces serial scan) ----------------
__global__ __launch_bounds__(512) void scan_lds(const int* __restrict__ bsum,
                                                int* __restrict__ boff, int nb) {
    __shared__ int s[512];
    int tid = threadIdx.x;
    int v = (tid < nb) ? bsum[tid] : 0;
    s[tid] = v;
    __syncthreads();
    for (int off = 1; off < 512; off <<= 1) {
        int t = 0;
        if (tid >= off) t = s[tid - off];
        __syncthreads();
        if (tid >= off) s[tid] += t;
        __syncthreads();
    }
    if (tid < nb) boff[tid] = s[tid] - v;   // exclusive
}

// ---------------- per-node CSR offsets + inv-sqrt degrees ----------------
__global__ __launch_bounds__(256) void node_offsets(const int* __restrict__ deg_in,
                                                    const int* __restrict__ deg_out,
                                                    const int* __restrict__ boff,
                                                    int* __restrict__ row_start,
                                                    int* __restrict__ cursor,
                                                    float* __restrict__ inv_in,
                                                    float* __restrict__ inv_out) {
    __shared__ int s[256];
    int i = blockIdx.x * 256 + threadIdx.x;
    int d = (i < N_NODES) ? deg_in[i] : 0;
    s[threadIdx.x] = d;
    __syncthreads();
    for (int off = 1; off < 256; off <<= 1) {
        int v = 0;
        if (threadIdx.x >= off) v = s[threadIdx.x - off];
        __syncthreads();
        if (threadIdx.x >= off) s[threadIdx.x] += v;
        __syncthreads();
    }
    if (i < N_NODES) {
        int excl = s[threadIdx.x] - d;
        int rs = boff[blockIdx.x] + excl;
        row_start[i] = rs;
        cursor[i] = rs;
        int di = deg_in[i];
        int dout = deg_out[i];
        inv_in[i]  = (di   > 0) ? rsqrtf((float)di)   : 0.0f;
        inv_out[i] = (dout > 0) ? rsqrtf((float)dout) : 0.0f;
    }
}

// ---------------- fill CSR adjacency ----------------
__global__ __launch_bounds__(256) void fill_csr(const int* __restrict__ src,
                                                const int* __restrict__ dst,
                                                int* __restrict__ cursor,
                                                int* __restrict__ adj) {
    int e = blockIdx.x * blockDim.x + threadIdx.x;
    if (e < N_EDGES) {
        int pos = atomicAdd(&cursor[dst[e]], 1);
        adj[pos] = src[e];
    }
}

// ---------------- W [K][N] fp32 -> Bt [NPAD][Kpad] bf16 ----------------
__global__ __launch_bounds__(256) void conv_bt(const float* __restrict__ W, bf16* __restrict__ Bt,
                                               int K, int N, int Kpad) {
    int idx = blockIdx.x * 256 + threadIdx.x;
    int k = idx % Kpad;
    int n = idx / Kpad;
    if (n >= NPAD) return;
    bf16 v = (bf16)0.0f;
    if (k < K && n < N) v = (bf16)W[(size_t)k * N + n];
    Bt[(size_t)n * Kpad + k] = v;
}

// ---------------- pad bias / Wfc ----------------
__global__ __launch_bounds__(256) void prep_small(const float* __restrict__ b1,
                                                  const float* __restrict__ b2,
                                                  const float* __restrict__ Wfc,
                                                  float* __restrict__ b1p,
                                                  float* __restrict__ b2p,
                                                  float* __restrict__ wfcp) {
    int i = blockIdx.x * 256 + threadIdx.x;
    if (i < NPAD) {
        b1p[i] = (i < D_H) ? b1[i] : 0.f;
        b2p[i] = (i < D_H) ? b2[i] : 0.f;
    }
    if (i < NPAD * 2) {
        wfcp[i] = (i < D_H * 2) ? Wfc[i] : 0.f;
    }
}

// ---------------- stream-A GEMM: 32 rows x full N=320, barrier-free K-loop ----------------
// Phase 1: stream the block's CONTIGUOUS A rows (fp32 x or bf16 h) -> bf16 swizzled LDS.
// Phase 2: K-loop reads A-frags from LDS and B-frags DIRECTLY from L2-resident Bt.
// No barriers/vmcnt drains in the loop. LDS = 32*Kpad*2 B (40 KB for K=640).
template<int NK, bool AF32>
__global__ __launch_bounds__(256) void gemm_stream(const float* __restrict__ Af,
                                                   const bf16* __restrict__ Ab,
                                                   const bf16* __restrict__ Bt,
                                                   const float* __restrict__ rowscale,
                                                   unsigned char* __restrict__ C8,
                                                   int M) {
    __shared__ bf16 As[32 * NK * 64];
    const int tid = threadIdx.x;
    const int lane = tid & 63;
    const int wc = tid >> 6;        // wave 0..3 -> 80-col slice
    const int blockRow = blockIdx.x * 32;
    const int Kpad = NK * 64;

    // ---- phase 1: stream A ----
    // chunk c covers K-tile c: 32 rows x 128 B (swizzled slots)
    #pragma unroll
    for (int c = 0; c < NK; ++c) {
        int o = c * 4096 + tid * 16;
        int row = (o >> 7) & 31;
        int slot = (o >> 4) & 7;
        int srck = c * 64 + (slot ^ (row & 7)) * 8;
        int gr = blockRow + row;
        bf16x8 v = {};
        if (AF32) {
            if (gr < N_NODES && srck < D_IN) {
                const float* p = Af + (size_t)gr * D_IN + srck;
                float4 f0 = *(const float4*)p;
                float4 f1 = *(const float4*)(p + 4);
                v[0] = (bf16)f0.x; v[1] = (bf16)f0.y; v[2] = (bf16)f0.z; v[3] = (bf16)f0.w;
                v[4] = (bf16)f1.x; v[5] = (bf16)f1.y; v[6] = (bf16)f1.z; v[7] = (bf16)f1.w;
            }
        } else {
            if (gr < N_NODES) {
                v = *(const bf16x8*)(Ab + (size_t)gr * Kpad + srck);
            }
        }
        *(bf16x8*)((char*)As + o) = v;
    }
    __syncthreads();

    // ---- phase 2: barrier-free K-loop ----
    f32x4 acc[2][5] = {};
    for (int t = 0; t < NK; ++t) {
        #pragma unroll
        for (int kk = 0; kk < 2; ++kk) {
            int slot = kk * 4 + (lane >> 4);
            bf16x8 af[2], bfr[5];
            #pragma unroll
            for (int mi = 0; mi < 2; ++mi) {
                int row = mi * 16 + (lane & 15);
                int addr = t * 4096 + row * 128 + ((slot ^ (row & 7)) << 4);
                af[mi] = *(const bf16x8*)((const char*)As + addr);
            }
            #pragma unroll
            for (int ni = 0; ni < 5; ++ni) {
                int brow = wc * 80 + ni * 16 + (lane & 15);
                bfr[ni] = *(const bf16x8*)(Bt + (size_t)brow * Kpad + t * 64 + slot * 8);
            }
            #pragma unroll
            for (int mi = 0; mi < 2; ++mi)
                #pragma unroll
                for (int ni = 0; ni < 5; ++ni)
                    acc[mi][ni] = __builtin_amdgcn_mfma_f32_16x16x32_bf16(af[mi], bfr[ni], acc[mi][ni], 0, 0, 0);
        }
    }

    // ---- shfl-transpose fp8 epilogue (rows 32, mi<2) ----
    {
        const int qs = lane >> 4;
        const int io = (lane >> 2) & 3;
        const int cgo = lane & 3;
        #pragma unroll
        for (int mi = 0; mi < 2; ++mi) {
            int rbase = blockRow + mi * 16;
            float4 s4 = *(const float4*)(rowscale + rbase + qs * 4);
            int gr = rbase + qs * 4 + io;
            #pragma unroll
            for (int ni = 0; ni < 5; ++ni) {
                unsigned int D = (unsigned int)ff8(acc[mi][ni][0] * s4.x)
                               | ((unsigned int)ff8(acc[mi][ni][1] * s4.y) << 8)
                               | ((unsigned int)ff8(acc[mi][ni][2] * s4.z) << 16)
                               | ((unsigned int)ff8(acc[mi][ni][3] * s4.w) << 24);
                int sbase = (lane & 48) + (cgo << 2);
                unsigned int S0 = (unsigned int)__shfl((int)D, sbase + 0);
                unsigned int S1 = (unsigned int)__shfl((int)D, sbase + 1);
                unsigned int S2 = (unsigned int)__shfl((int)D, sbase + 2);
                unsigned int S3 = (unsigned int)__shfl((int)D, sbase + 3);
                int sh = io * 8;
                unsigned int out = ((S0 >> sh) & 0xffu)
                                 | (((S1 >> sh) & 0xffu) << 8)
                                 | (((S2 >> sh) & 0xffu) << 16)
                                 | (((S3 >> sh) & 0xffu) << 24);
                if (gr < M) {
                    int gc = wc * 80 + ni * 16 + (cgo << 2);
                    *(unsigned int*)(C8 + (size_t)gr * NPAD + gc) = out;
                }
            }
        }
    }
}

// ---------------- fp8 gather core: wave-per-node, HW byte-select converts, unroll x8 ----------
__device__ __forceinline__ void gather_fp8(const unsigned char* __restrict__ m8,
                                           const int* __restrict__ adj,
                                           int s, int d, int lane, float acc[5]) {
    const int cb = lane * 4;
    const int c4 = 256 + lane;
    int e = 0;
    for (; e + 8 <= d; e += 8) {
        unsigned int u[8], b[8];
        #pragma unroll
        for (int j = 0; j < 8; ++j) {
            const unsigned char* r = m8 + (size_t)adj[s + e + j] * NPAD;
            u[j] = *(const unsigned int*)(r + cb);
            b[j] = r[c4];
        }
        #pragma unroll
        for (int j = 0; j < 8; ++j) {
            f32x2 lo = __builtin_amdgcn_cvt_pk_f32_fp8(u[j], false);
            f32x2 hi = __builtin_amdgcn_cvt_pk_f32_fp8(u[j], true);
            acc[0] += lo[0]; acc[1] += lo[1]; acc[2] += hi[0]; acc[3] += hi[1];
            acc[4] += __builtin_amdgcn_cvt_f32_fp8(b[j], 0);
        }
    }
    if (e + 4 <= d) {
        unsigned int u[4], b[4];
        #pragma unroll
        for (int j = 0; j < 4; ++j) {
            const unsigned char* r = m8 + (size_t)adj[s + e + j] * NPAD;
            u[j] = *(const unsigned int*)(r + cb);
            b[j] = r[c4];
        }
        #pragma unroll
        for (int j = 0; j < 4; ++j) {
            f32x2 lo = __builtin_amdgcn_cvt_pk_f32_fp8(u[j], false);
            f32x2 hi = __builtin_amdgcn_cvt_pk_f32_fp8(u[j], true);
            acc[0] += lo[0]; acc[1] += lo[1]; acc[2] += hi[0]; acc[3] += hi[1];
            acc[4] += __builtin_amdgcn_cvt_f32_fp8(b[j], 0);
        }
        e += 4;
    }
    for (; e < d; ++e) {
        const unsigned char* r = m8 + (size_t)adj[s + e] * NPAD;
        unsigned int u = *(const unsigned int*)(r + cb);
        unsigned int b = r[c4];
        f32x2 lo = __builtin_amdgcn_cvt_pk_f32_fp8(u, false);
        f32x2 hi = __builtin_amdgcn_cvt_pk_f32_fp8(u, true);
        acc[0] += lo[0]; acc[1] += lo[1]; acc[2] += hi[0]; acc[3] += hi[1];
        acc[4] += __builtin_amdgcn_cvt_f32_fp8(b, 0);
    }
}

// ---------------- layer-1 aggregation: h = relu(inv_in * sum m[adj] + bias) ----------------
__global__ __launch_bounds__(256) void aggregate_fp8(const unsigned char* __restrict__ m8,
                                                     const int* __restrict__ row_start,
                                                     const int* __restrict__ deg_in,
                                                     const int* __restrict__ adj,
                                                     const float* __restrict__ inv_in,
                                                     const float* __restrict__ biasp,
                                                     bf16* __restrict__ h) {
    int node = (int)((blockIdx.x * (size_t)blockDim.x + threadIdx.x) >> 6);
    int lane = threadIdx.x & 63;
    if (node >= N_NODES) return;
    int s = row_start[node];
    int d = deg_in[node];
    float acc[5] = {};
    gather_fp8(m8, adj, s, d, lane, acc);
    float sc = inv_in[node];
    int cA = lane * 4;
    int c4 = 256 + lane;
    float4 bq = *(const float4*)(biasp + cA);
    bf16* out = h + (size_t)node * NPAD;
    __bf16 o4[4];
    o4[0] = (bf16)fmaxf(acc[0] * sc + bq.x, 0.f);
    o4[1] = (bf16)fmaxf(acc[1] * sc + bq.y, 0.f);
    o4[2] = (bf16)fmaxf(acc[2] * sc + bq.z, 0.f);
    o4[3] = (bf16)fmaxf(acc[3] * sc + bq.w, 0.f);
    *(float2*)(out + cA) = *(float2*)o4;
    out[c4] = (bf16)fmaxf(acc[4] * sc + biasp[c4], 0.f);
}

// ---------------- fused layer-2 aggregation + fc + softmax + pooling ----------------
__global__ __launch_bounds__(256) void agg2_fc_pool(const unsigned char* __restrict__ m8,
                                                    const int* __restrict__ row_start,
                                                    const int* __restrict__ deg_in,
                                                    const int* __restrict__ adj,
                                                    const float* __restrict__ inv_in,
                                                    const float* __restrict__ biasp,
                                                    const float* __restrict__ wfcp,
                                                    const float* __restrict__ bfc,
                                                    const int* __restrict__ gid,
                                                    float* __restrict__ pooled,
                                                    int* __restrict__ gcount) {
    int node = (int)((blockIdx.x * (size_t)blockDim.x + threadIdx.x) >> 6);
    int lane = threadIdx.x & 63;
    if (node >= N_NODES) return;
    int s = row_start[node];
    int d = deg_in[node];
    float acc[5] = {};
    gather_fp8(m8, adj, s, d, lane, acc);
    float sc = inv_in[node];
    int cA = lane * 4;
    int c4 = 256 + lane;
    float4 bq = *(const float4*)(biasp + cA);
    float h0 = fmaxf(acc[0] * sc + bq.x, 0.f);
    float h1 = fmaxf(acc[1] * sc + bq.y, 0.f);
    float h2 = fmaxf(acc[2] * sc + bq.z, 0.f);
    float h3 = fmaxf(acc[3] * sc + bq.w, 0.f);
    float h4 = fmaxf(acc[4] * sc + biasp[c4], 0.f);
    float4 wA0 = *(const float4*)(wfcp + cA * 2);
    float4 wA1 = *(const float4*)(wfcp + cA * 2 + 4);
    float z0 = h0 * wA0.x + h1 * wA0.z + h2 * wA1.x + h3 * wA1.z;
    float z1 = h0 * wA0.y + h1 * wA0.w + h2 * wA1.y + h3 * wA1.w;
    z0 += h4 * wfcp[c4 * 2];
    z1 += h4 * wfcp[c4 * 2 + 1];
    for (int off = 32; off; off >>= 1) {
        z0 += __shfl_down(z0, off);
        z1 += __shfl_down(z1, off);
    }
    if (lane == 0) {
        float s0 = z0 + bfc[0], s1 = z1 + bfc[1];
        float mx = fmaxf(s0, s1);
        float e0 = __expf(s0 - mx), e1 = __expf(s1 - mx);
        float inv = 1.f / (e0 + e1);
        int g = gid[node];
        atomicAdd(&pooled[g * 2 + 0], e0 * inv);
        atomicAdd(&pooled[g * 2 + 1], e1 * inv);
        atomicAdd(&gcount[g], 1);
    }
}

// ---------------- finalize: divide by counts ----------------
__global__ __launch_bounds__(256) void finalize(const float* __restrict__ pooled,
                                                const int* __restrict__ gcount,
                                                float* __restrict__ out) {
    int i = blockIdx.x * blockDim.x + threadIdx.x;
    if (i < N_GRAPHS * 2) {
        int g = i >> 1;
        float c = (float)max(gcount[g], 1);
        out[i] = pooled[i] / c;
    }
}

extern "C" void kernel_launch(void* const* d_in, const int* in_sizes, int n_in,
                              void* d_out, int out_size, void* d_ws, size_t ws_size,
                              hipStream_t stream) {
    const float* x   = (const float*)d_in[0];
    const float* W1  = (const float*)d_in[1];
    const float* b1  = (const float*)d_in[2];
    const float* W2  = (const float*)d_in[3];
    const float* b2  = (const float*)d_in[4];
    const float* Wfc = (const float*)d_in[5];
    const float* bfc = (const float*)d_in[6];
    const int* src   = (const int*)d_in[7];
    const int* dst   = (const int*)d_in[8];
    const int* gid   = (const int*)d_in[9];

    char* ws = (char*)d_ws;
    size_t off = 0;
    auto alloc = [&](size_t bytes) -> void* {
        void* p = ws + off;
        off = (off + bytes + 255) & ~(size_t)255;
        return p;
    };
    bf16* h_bf            = (bf16*)alloc((size_t)MPAD * NPAD * 2);         // 64.1 MB
    unsigned char* m8     = (unsigned char*)alloc((size_t)N_NODES * NPAD); // 32 MB
    bf16* B1t    = (bf16*)alloc((size_t)NPAD * K1PAD * 2);
    bf16* B2t    = (bf16*)alloc((size_t)NPAD * K2PAD * 2);
    int*   adj      = (int*)alloc((size_t)N_EDGES * 4);
    int*   row_st   = (int*)alloc((size_t)N_NODES * 4);
    int*   cursor   = (int*)alloc((size_t)N_NODES * 4);
    int*   deg_in   = (int*)alloc((size_t)N_NODES * 4);
    int*   deg_out  = (int*)alloc((size_t)N_NODES * 4);
    float* inv_in   = (float*)alloc((size_t)N_NODES * 4);
    float* inv_out  = (float*)alloc((size_t)N_NODES * 4);
    const int NB = (N_NODES + 255) / 256;   // 391
    int*   bsum     = (int*)alloc((size_t)NB * 4);
    int*   boff     = (int*)alloc((size_t)NB * 4);
    float* pooled   = (float*)alloc((size_t)N_GRAPHS * 2 * 4);
    int*   gcount   = (int*)alloc((size_t)N_GRAPHS * 4);
    float* b1p      = (float*)alloc((size_t)NPAD * 4);
    float* b2p      = (float*)alloc((size_t)NPAD * 4);
    float* wfcp     = (float*)alloc((size_t)NPAD * 2 * 4);

    hipMemsetAsync(deg_in, 0, (size_t)N_NODES * 4, stream);
    hipMemsetAsync(deg_out, 0, (size_t)N_NODES * 4, stream);
    hipMemsetAsync(pooled, 0, (size_t)N_GRAPHS * 2 * 4, stream);
    hipMemsetAsync(gcount, 0, (size_t)N_GRAPHS * 4, stream);

    // graph preprocessing
    count_deg<<<(N_EDGES + 255) / 256, 256, 0, stream>>>(src, dst, deg_out, deg_in);
    block_sum<<<NB, 256, 0, stream>>>(deg_in, bsum);
    scan_lds<<<1, 512, 0, stream>>>(bsum, boff, NB);
    node_offsets<<<NB, 256, 0, stream>>>(deg_in, deg_out, boff, row_st, cursor, inv_in, inv_out);
    fill_csr<<<(N_EDGES + 255) / 256, 256, 0, stream>>>(src, dst, cursor, adj);

    // weight conversions + padded small tensors
    conv_bt<<<(NPAD * K1PAD + 255) / 256, 256, 0, stream>>>(W1, B1t, D_IN, D_H, K1PAD);
    conv_bt<<<(NPAD * K2PAD + 255) / 256, 256, 0, stream>>>(W2, B2t, D_H, D_H, K2PAD);
    prep_small<<<3, 256, 0, stream>>>(b1, b2, Wfc, b1p, b2p, wfcp);

    // layer 1 (stream fp32 A, L2-direct B, fp8 m output)
    gemm_stream<10, true><<<MPAD / 32, 256, 0, stream>>>(x, nullptr, B1t, inv_out, m8, N_NODES);
    aggregate_fp8<<<(N_NODES * 64 + 255) / 256, 256, 0, stream>>>(m8, row_st, deg_in, adj, inv_in, b1p, h_bf);
    // layer 2 (stream bf16 A)
    gemm_stream<5, false><<<MPAD / 32, 256, 0, stream>>>(nullptr, h_bf, B2t, inv_out, m8, N_NODES);
    // fused layer-2 aggregate + fc + softmax + pooling
    agg2_fc_pool<<<(N_NODES * 64 + 255) / 256, 256, 0, stream>>>(m8, row_st, deg_in, adj, inv_in, b2p,
                                                                 wfcp, bfc, gid, pooled, gcount);
    finalize<<<(N_GRAPHS * 2 + 255) / 256, 256, 0, stream>>>(pooled, gcount, (float*)d_out);
}

// Round 16
// 672.533 us; speedup vs baseline: 1.1790x; 1.1790x over previous
//
#include <hip/hip_runtime.h>
#include <hip/hip_bf16.h>
#include <hip/hip_fp8.h>

#define N_NODES 100000
#define N_EDGES 1600000
#define N_GRAPHS 2000
#define D_IN 600
#define D_H 300
#define D_OUT 2

#define NPAD 320        // padded hidden width (multiple of 64)
#define K1PAD 640       // padded K for layer-1 GEMM
#define K2PAD 320       // padded K for layer-2 GEMM
#define MPAD 100096     // 782 * 128

typedef __bf16 bf16;
typedef __bf16 bf16x8 __attribute__((ext_vector_type(8)));
typedef float f32x4 __attribute__((ext_vector_type(4)));
typedef float f32x2 __attribute__((ext_vector_type(2)));

__device__ __forceinline__ unsigned char ff8(float f) {
    __hip_fp8_e4m3 t(f); return (unsigned char)t.__x;
}

// ---------------- degree counting ----------------
__global__ __launch_bounds__(256) void count_deg(const int* __restrict__ src,
                                                 const int* __restrict__ dst,
                                                 int* __restrict__ deg_out,
                                                 int* __restrict__ deg_in) {
    int e = blockIdx.x * blockDim.x + threadIdx.x;
    if (e < N_EDGES) {
        atomicAdd(&deg_out[src[e]], 1);
        atomicAdd(&deg_in[dst[e]], 1);
    }
}

// ---------------- per-block sums of deg_in ----------------
__global__ __launch_bounds__(256) void block_sum(const int* __restrict__ deg_in,
                                                 int* __restrict__ bsum) {
    __shared__ int s[256];
    int i = blockIdx.x * 256 + threadIdx.x;
    s[threadIdx.x] = (i < N_NODES) ? deg_in[i] : 0;
    __syncthreads();
    for (int off = 128; off; off >>= 1) {
        if (threadIdx.x < off) s[threadIdx.x] += s[threadIdx.x + off];
        __syncthreads();
    }
    if (threadIdx.x == 0) bsum[blockIdx.x] = s[0];
}

// ---------------- one-block LDS scan over block sums (replaces serial scan) ----------------
__global__ __launch_bounds__(512) void scan_lds(const int* __restrict__ bsum,
                                                int* __restrict__ boff, int nb) {
    __shared__ int s[512];
    int tid = threadIdx.x;
    int v = (tid < nb) ? bsum[tid] : 0;
    s[tid] = v;
    __syncthreads();
    for (int off = 1; off < 512; off <<= 1) {
        int t = 0;
        if (tid >= off) t = s[tid - off];
        __syncthreads();
        if (tid >= off) s[tid] += t;
        __syncthreads();
    }
    if (tid < nb) boff[tid] = s[tid] - v;   // exclusive
}

// ---------------- per-node CSR offsets + inv-sqrt degrees ----------------
__global__ __launch_bounds__(256) void node_offsets(const int* __restrict__ deg_in,
                                                    const int* __restrict__ deg_out,
                                                    const int* __restrict__ boff,
                                                    int* __restrict__ row_start,
                                                    int* __restrict__ cursor,
                                                    float* __restrict__ inv_in,
                                                    float* __restrict__ inv_out) {
    __shared__ int s[256];
    int i = blockIdx.x * 256 + threadIdx.x;
    int d = (i < N_NODES) ? deg_in[i] : 0;
    s[threadIdx.x] = d;
    __syncthreads();
    for (int off = 1; off < 256; off <<= 1) {
        int v = 0;
        if (threadIdx.x >= off) v = s[threadIdx.x - off];
        __syncthreads();
        if (threadIdx.x >= off) s[threadIdx.x] += v;
        __syncthreads();
    }
    if (i < N_NODES) {
        int excl = s[threadIdx.x] - d;
        int rs = boff[blockIdx.x] + excl;
        row_start[i] = rs;
        cursor[i] = rs;
        int di = deg_in[i];
        int dout = deg_out[i];
        inv_in[i]  = (di   > 0) ? rsqrtf((float)di)   : 0.0f;
        inv_out[i] = (dout > 0) ? rsqrtf((float)dout) : 0.0f;
    }
}

// ---------------- fill CSR adjacency ----------------
__global__ __launch_bounds__(256) void fill_csr(const int* __restrict__ src,
                                                const int* __restrict__ dst,
                                                int* __restrict__ cursor,
                                                int* __restrict__ adj) {
    int e = blockIdx.x * blockDim.x + threadIdx.x;
    if (e < N_EDGES) {
        int pos = atomicAdd(&cursor[dst[e]], 1);
        adj[pos] = src[e];
    }
}

// ---------------- W [K][N] fp32 -> Bt [NPAD][Kpad] bf16 ----------------
__global__ __launch_bounds__(256) void conv_bt(const float* __restrict__ W, bf16* __restrict__ Bt,
                                               int K, int N, int Kpad) {
    int idx = blockIdx.x * 256 + threadIdx.x;
    int k = idx % Kpad;
    int n = idx / Kpad;
    if (n >= NPAD) return;
    bf16 v = (bf16)0.0f;
    if (k < K && n < N) v = (bf16)W[(size_t)k * N + n];
    Bt[(size_t)n * Kpad + k] = v;
}

// ---------------- pad bias / Wfc ----------------
__global__ __launch_bounds__(256) void prep_small(const float* __restrict__ b1,
                                                  const float* __restrict__ b2,
                                                  const float* __restrict__ Wfc,
                                                  float* __restrict__ b1p,
                                                  float* __restrict__ b2p,
                                                  float* __restrict__ wfcp) {
    int i = blockIdx.x * 256 + threadIdx.x;
    if (i < NPAD) {
        b1p[i] = (i < D_H) ? b1[i] : 0.f;
        b2p[i] = (i < D_H) ? b2[i] : 0.f;
    }
    if (i < NPAD * 2) {
        wfcp[i] = (i < D_H * 2) ? Wfc[i] : 0.f;
    }
}

// ---------------- reg-staged MFMA GEMM, 128x160 tile, shfl-transpose fp8 epilogue ----------------
template<int NK, bool AF32>
__global__ __launch_bounds__(256) void gemm_rs(const float* __restrict__ Af,
                                               const bf16* __restrict__ Ab,
                                               const bf16* __restrict__ Bt,
                                               const float* __restrict__ rowscale,
                                               unsigned char* __restrict__ C8,
                                               int M) {
    __shared__ bf16 As[128 * 64];   // 16 KB
    __shared__ bf16 Bs[160 * 64];   // 20 KB
    const int tid = threadIdx.x;
    const int lane = tid & 63;
    const int wid = tid >> 6;       // 0..3
    const int wr = wid >> 1;        // 0..1 -> 64-row half
    const int wc = wid & 1;         // 0..1 -> 80-col half
    const int blockRow = blockIdx.x * 128;
    const int blockCol = blockIdx.y * 160;
    const int Kpad = NK * 64;
    const size_t rowBytes = (size_t)Kpad * 2;

    f32x4 acc[4][5] = {};

    int aO[4], aRow[4], aKs[4];
    #pragma unroll
    for (int c = 0; c < 4; ++c) {
        int o = c * 4096 + tid * 16;
        int row = o >> 7;
        int slot = (o >> 4) & 7;
        aO[c] = o; aRow[c] = row; aKs[c] = (slot ^ (row & 7)) * 8;
    }
    int bO[5], bRow[5], bKs[5];
    #pragma unroll
    for (int c = 0; c < 5; ++c) {
        int o = c * 4096 + tid * 16;
        int row = o >> 7;
        int slot = (o >> 4) & 7;
        bO[c] = o; bRow[c] = row; bKs[c] = (slot ^ (row & 7)) * 8;
    }

    float4 fA[4][2];
    bf16x8 sA[4];
    bf16x8 sB[5];

    auto loadTile = [&](int t) {
        #pragma unroll
        for (int c = 0; c < 4; ++c) {
            if (AF32) {
                int gr = blockRow + aRow[c];
                int k = t * 64 + aKs[c];
                if (gr < N_NODES && k < D_IN) {
                    const float* p = Af + (size_t)gr * D_IN + k;
                    fA[c][0] = *(const float4*)p;
                    fA[c][1] = *(const float4*)(p + 4);
                } else {
                    fA[c][0] = make_float4(0.f, 0.f, 0.f, 0.f);
                    fA[c][1] = make_float4(0.f, 0.f, 0.f, 0.f);
                }
            } else {
                const char* g = (const char*)Ab + (size_t)(blockRow + aRow[c]) * rowBytes
                                + (size_t)t * 128 + aKs[c] * 2;
                sA[c] = *(const bf16x8*)g;
            }
        }
        #pragma unroll
        for (int c = 0; c < 5; ++c) {
            const char* g = (const char*)Bt + (size_t)(blockCol + bRow[c]) * rowBytes
                            + (size_t)t * 128 + bKs[c] * 2;
            sB[c] = *(const bf16x8*)g;
        }
    };

    loadTile(0);

    for (int t = 0; t < NK; ++t) {
        __syncthreads();
        #pragma unroll
        for (int c = 0; c < 4; ++c) {
            bf16x8 v;
            if (AF32) {
                v[0] = (bf16)fA[c][0].x; v[1] = (bf16)fA[c][0].y;
                v[2] = (bf16)fA[c][0].z; v[3] = (bf16)fA[c][0].w;
                v[4] = (bf16)fA[c][1].x; v[5] = (bf16)fA[c][1].y;
                v[6] = (bf16)fA[c][1].z; v[7] = (bf16)fA[c][1].w;
            } else {
                v = sA[c];
            }
            *(bf16x8*)((char*)As + aO[c]) = v;
        }
        #pragma unroll
        for (int c = 0; c < 5; ++c)
            *(bf16x8*)((char*)Bs + bO[c]) = sB[c];
        __syncthreads();
        if (t + 1 < NK) loadTile(t + 1);
        #pragma unroll
        for (int kk = 0; kk < 2; ++kk) {
            int slot = kk * 4 + (lane >> 4);
            bf16x8 af[4], bfr[5];
            #pragma unroll
            for (int mi = 0; mi < 4; ++mi) {
                int row = wr * 64 + mi * 16 + (lane & 15);
                int addr = row * 128 + ((slot ^ (row & 7)) << 4);
                af[mi] = *(const bf16x8*)((const char*)As + addr);
            }
            #pragma unroll
            for (int ni = 0; ni < 5; ++ni) {
                int row = wc * 80 + ni * 16 + (lane & 15);
                int addr = row * 128 + ((slot ^ (row & 7)) << 4);
                bfr[ni] = *(const bf16x8*)((const char*)Bs + addr);
            }
            #pragma unroll
            for (int mi = 0; mi < 4; ++mi)
                #pragma unroll
                for (int ni = 0; ni < 5; ++ni)
                    acc[mi][ni] = __builtin_amdgcn_mfma_f32_16x16x32_bf16(af[mi], bfr[ni], acc[mi][ni], 0, 0, 0);
        }
    }
    // ---- shfl-transpose epilogue ----
    {
        const int qs = lane >> 4;
        const int qo = lane >> 4;
        const int io = (lane >> 2) & 3;
        const int cgo = lane & 3;
        #pragma unroll
        for (int mi = 0; mi < 4; ++mi) {
            int rbase = blockRow + wr * 64 + mi * 16;
            float4 s4 = *(const float4*)(rowscale + rbase + qs * 4);
            int gr = rbase + qo * 4 + io;
            #pragma unroll
            for (int ni = 0; ni < 5; ++ni) {
                unsigned int D = (unsigned int)ff8(acc[mi][ni][0] * s4.x)
                               | ((unsigned int)ff8(acc[mi][ni][1] * s4.y) << 8)
                               | ((unsigned int)ff8(acc[mi][ni][2] * s4.z) << 16)
                               | ((unsigned int)ff8(acc[mi][ni][3] * s4.w) << 24);
                int sbase = (lane & 48) + (cgo << 2);
                unsigned int S0 = (unsigned int)__shfl((int)D, sbase + 0);
                unsigned int S1 = (unsigned int)__shfl((int)D, sbase + 1);
                unsigned int S2 = (unsigned int)__shfl((int)D, sbase + 2);
                unsigned int S3 = (unsigned int)__shfl((int)D, sbase + 3);
                int sh = io * 8;
                unsigned int out = ((S0 >> sh) & 0xffu)
                                 | (((S1 >> sh) & 0xffu) << 8)
                                 | (((S2 >> sh) & 0xffu) << 16)
                                 | (((S3 >> sh) & 0xffu) << 24);
                if (gr < M) {
                    int gc = blockCol + wc * 80 + ni * 16 + (cgo << 2);
                    *(unsigned int*)(C8 + (size_t)gr * NPAD + gc) = out;
                }
            }
        }
    }
}

// ---------------- fp8 gather core: wave-per-node, HW byte-select converts, unroll x8 ----------
__device__ __forceinline__ void gather_fp8(const unsigned char* __restrict__ m8,
                                           const int* __restrict__ adj,
                                           int s, int d, int lane, float acc[5]) {
    const int cb = lane * 4;
    const int c4 = 256 + lane;
    int e = 0;
    for (; e + 8 <= d; e += 8) {
        unsigned int u[8], b[8];
        #pragma unroll
        for (int j = 0; j < 8; ++j) {
            const unsigned char* r = m8 + (size_t)adj[s + e + j] * NPAD;
            u[j] = *(const unsigned int*)(r + cb);
            b[j] = r[c4];
        }
        #pragma unroll
        for (int j = 0; j < 8; ++j) {
            f32x2 lo = __builtin_amdgcn_cvt_pk_f32_fp8(u[j], false);
            f32x2 hi = __builtin_amdgcn_cvt_pk_f32_fp8(u[j], true);
            acc[0] += lo[0]; acc[1] += lo[1]; acc[2] += hi[0]; acc[3] += hi[1];
            acc[4] += __builtin_amdgcn_cvt_f32_fp8(b[j], 0);
        }
    }
    if (e + 4 <= d) {
        unsigned int u[4], b[4];
        #pragma unroll
        for (int j = 0; j < 4; ++j) {
            const unsigned char* r = m8 + (size_t)adj[s + e + j] * NPAD;
            u[j] = *(const unsigned int*)(r + cb);
            b[j] = r[c4];
        }
        #pragma unroll
        for (int j = 0; j < 4; ++j) {
            f32x2 lo = __builtin_amdgcn_cvt_pk_f32_fp8(u[j], false);
            f32x2 hi = __builtin_amdgcn_cvt_pk_f32_fp8(u[j], true);
            acc[0] += lo[0]; acc[1] += lo[1]; acc[2] += hi[0]; acc[3] += hi[1];
            acc[4] += __builtin_amdgcn_cvt_f32_fp8(b[j], 0);
        }
        e += 4;
    }
    for (; e < d; ++e) {
        const unsigned char* r = m8 + (size_t)adj[s + e] * NPAD;
        unsigned int u = *(const unsigned int*)(r + cb);
        unsigned int b = r[c4];
        f32x2 lo = __builtin_amdgcn_cvt_pk_f32_fp8(u, false);
        f32x2 hi = __builtin_amdgcn_cvt_pk_f32_fp8(u, true);
        acc[0] += lo[0]; acc[1] += lo[1]; acc[2] += hi[0]; acc[3] += hi[1];
        acc[4] += __builtin_amdgcn_cvt_f32_fp8(b, 0);
    }
}

// ---------------- layer-1 aggregation: h = relu(inv_in * sum m[adj] + bias) ----------------
__global__ __launch_bounds__(256) void aggregate_fp8(const unsigned char* __restrict__ m8,
                                                     const int* __restrict__ row_start,
                                                     const int* __restrict__ deg_in,
                                                     const int* __restrict__ adj,
                                                     const float* __restrict__ inv_in,
                                                     const float* __restrict__ biasp,
                                                     bf16* __restrict__ h) {
    int node = (int)((blockIdx.x * (size_t)blockDim.x + threadIdx.x) >> 6);
    int lane = threadIdx.x & 63;
    if (node >= N_NODES) return;
    int s = row_start[node];
    int d = deg_in[node];
    float acc[5] = {};
    gather_fp8(m8, adj, s, d, lane, acc);
    float sc = inv_in[node];
    int cA = lane * 4;
    int c4 = 256 + lane;
    float4 bq = *(const float4*)(biasp + cA);
    bf16* out = h + (size_t)node * NPAD;
    __bf16 o4[4];
    o4[0] = (bf16)fmaxf(acc[0] * sc + bq.x, 0.f);
    o4[1] = (bf16)fmaxf(acc[1] * sc + bq.y, 0.f);
    o4[2] = (bf16)fmaxf(acc[2] * sc + bq.z, 0.f);
    o4[3] = (bf16)fmaxf(acc[3] * sc + bq.w, 0.f);
    *(float2*)(out + cA) = *(float2*)o4;
    out[c4] = (bf16)fmaxf(acc[4] * sc + biasp[c4], 0.f);
}

// ---------------- fused layer-2 aggregation + fc + softmax + pooling ----------------
__global__ __launch_bounds__(256) void agg2_fc_pool(const unsigned char* __restrict__ m8,
                                                    const int* __restrict__ row_start,
                                                    const int* __restrict__ deg_in,
                                                    const int* __restrict__ adj,
                                                    const float* __restrict__ inv_in,
                                                    const float* __restrict__ biasp,
                                                    const float* __restrict__ wfcp,
                                                    const float* __restrict__ bfc,
                                                    const int* __restrict__ gid,
                                                    float* __restrict__ pooled,
                                                    int* __restrict__ gcount) {
    int node = (int)((blockIdx.x * (size_t)blockDim.x + threadIdx.x) >> 6);
    int lane = threadIdx.x & 63;
    if (node >= N_NODES) return;
    int s = row_start[node];
    int d = deg_in[node];
    float acc[5] = {};
    gather_fp8(m8, adj, s, d, lane, acc);
    float sc = inv_in[node];
    int cA = lane * 4;
    int c4 = 256 + lane;
    float4 bq = *(const float4*)(biasp + cA);
    float h0 = fmaxf(acc[0] * sc + bq.x, 0.f);
    float h1 = fmaxf(acc[1] * sc + bq.y, 0.f);
    float h2 = fmaxf(acc[2] * sc + bq.z, 0.f);
    float h3 = fmaxf(acc[3] * sc + bq.w, 0.f);
    float h4 = fmaxf(acc[4] * sc + biasp[c4], 0.f);
    float4 wA0 = *(const float4*)(wfcp + cA * 2);
    float4 wA1 = *(const float4*)(wfcp + cA * 2 + 4);
    float z0 = h0 * wA0.x + h1 * wA0.z + h2 * wA1.x + h3 * wA1.z;
    float z1 = h0 * wA0.y + h1 * wA0.w + h2 * wA1.y + h3 * wA1.w;
    z0 += h4 * wfcp[c4 * 2];
    z1 += h4 * wfcp[c4 * 2 + 1];
    for (int off = 32; off; off >>= 1) {
        z0 += __shfl_down(z0, off);
        z1 += __shfl_down(z1, off);
    }
    if (lane == 0) {
        float s0 = z0 + bfc[0], s1 = z1 + bfc[1];
        float mx = fmaxf(s0, s1);
        float e0 = __expf(s0 - mx), e1 = __expf(s1 - mx);
        float inv = 1.f / (e0 + e1);
        int g = gid[node];
        atomicAdd(&pooled[g * 2 + 0], e0 * inv);
        atomicAdd(&pooled[g * 2 + 1], e1 * inv);
        atomicAdd(&gcount[g], 1);
    }
}

// ---------------- finalize: divide by counts ----------------
__global__ __launch_bounds__(256) void finalize(const float* __restrict__ pooled,
                                                const int* __restrict__ gcount,
                                                float* __restrict__ out) {
    int i = blockIdx.x * blockDim.x + threadIdx.x;
    if (i < N_GRAPHS * 2) {
        int g = i >> 1;
        float c = (float)max(gcount[g], 1);
        out[i] = pooled[i] / c;
    }
}

extern "C" void kernel_launch(void* const* d_in, const int* in_sizes, int n_in,
                              void* d_out, int out_size, void* d_ws, size_t ws_size,
                              hipStream_t stream) {
    const float* x   = (const float*)d_in[0];
    const float* W1  = (const float*)d_in[1];
    const float* b1  = (const float*)d_in[2];
    const float* W2  = (const float*)d_in[3];
    const float* b2  = (const float*)d_in[4];
    const float* Wfc = (const float*)d_in[5];
    const float* bfc = (const float*)d_in[6];
    const int* src   = (const int*)d_in[7];
    const int* dst   = (const int*)d_in[8];
    const int* gid   = (const int*)d_in[9];

    char* ws = (char*)d_ws;
    size_t off = 0;
    auto alloc = [&](size_t bytes) -> void* {
        void* p = ws + off;
        off = (off + bytes + 255) & ~(size_t)255;
        return p;
    };
    bf16* h_bf            = (bf16*)alloc((size_t)MPAD * NPAD * 2);         // 64.1 MB
    unsigned char* m8     = (unsigned char*)alloc((size_t)N_NODES * NPAD); // 32 MB
    bf16* B1t    = (bf16*)alloc((size_t)NPAD * K1PAD * 2);
    bf16* B2t    = (bf16*)alloc((size_t)NPAD * K2PAD * 2);
    int*   adj      = (int*)alloc((size_t)N_EDGES * 4);
    int*   row_st   = (int*)alloc((size_t)N_NODES * 4);
    int*   cursor   = (int*)alloc((size_t)N_NODES * 4);
    int*   deg_in   = (int*)alloc((size_t)N_NODES * 4);
    int*   deg_out  = (int*)alloc((size_t)N_NODES * 4);
    float* inv_in   = (float*)alloc((size_t)N_NODES * 4);
    float* inv_out  = (float*)alloc((size_t)N_NODES * 4);
    const int NB = (N_NODES + 255) / 256;   // 391
    int*   bsum     = (int*)alloc((size_t)NB * 4);
    int*   boff     = (int*)alloc((size_t)NB * 4);
    float* pooled   = (float*)alloc((size_t)N_GRAPHS * 2 * 4);
    int*   gcount   = (int*)alloc((size_t)N_GRAPHS * 4);
    float* b1p      = (float*)alloc((size_t)NPAD * 4);
    float* b2p      = (float*)alloc((size_t)NPAD * 4);
    float* wfcp     = (float*)alloc((size_t)NPAD * 2 * 4);

    hipMemsetAsync(deg_in, 0, (size_t)N_NODES * 4, stream);
    hipMemsetAsync(deg_out, 0, (size_t)N_NODES * 4, stream);
    hipMemsetAsync(pooled, 0, (size_t)N_GRAPHS * 2 * 4, stream);
    hipMemsetAsync(gcount, 0, (size_t)N_GRAPHS * 4, stream);

    // graph preprocessing
    count_deg<<<(N_EDGES + 255) / 256, 256, 0, stream>>>(src, dst, deg_out, deg_in);
    block_sum<<<NB, 256, 0, stream>>>(deg_in, bsum);
    scan_lds<<<1, 512, 0, stream>>>(bsum, boff, NB);
    node_offsets<<<NB, 256, 0, stream>>>(deg_in, deg_out, boff, row_st, cursor, inv_in, inv_out);
    fill_csr<<<(N_EDGES + 255) / 256, 256, 0, stream>>>(src, dst, cursor, adj);

    // weight conversions + padded small tensors
    conv_bt<<<(NPAD * K1PAD + 255) / 256, 256, 0, stream>>>(W1, B1t, D_IN, D_H, K1PAD);
    conv_bt<<<(NPAD * K2PAD + 255) / 256, 256, 0, stream>>>(W2, B2t, D_H, D_H, K2PAD);
    prep_small<<<3, 256, 0, stream>>>(b1, b2, Wfc, b1p, b2p, wfcp);

    dim3 ggrid(MPAD / 128, 2);   // 782 x 2 column-halves

    // layer 1 (reg-staged fp32 A, fp8 m output)
    gemm_rs<10, true><<<ggrid, 256, 0, stream>>>(x, nullptr, B1t, inv_out, m8, N_NODES);
    aggregate_fp8<<<(N_NODES * 64 + 255) / 256, 256, 0, stream>>>(m8, row_st, deg_in, adj, inv_in, b1p, h_bf);
    // layer 2 (reg-staged bf16 A)
    gemm_rs<5, false><<<ggrid, 256, 0, stream>>>(nullptr, h_bf, B2t, inv_out, m8, N_NODES);
    // fused layer-2 aggregate + fc + softmax + pooling
    agg2_fc_pool<<<(N_NODES * 64 + 255) / 256, 256, 0, stream>>>(m8, row_st, deg_in, adj, inv_in, b2p,
                                                                 wfcp, bfc, gid, pooled, gcount);
    finalize<<<(N_GRAPHS * 2 + 255) / 256, 256, 0, stream>>>(pooled, gcount, (float*)d_out);
}